// Round 4
// baseline (699.208 us; speedup 1.0000x reference)
//
#include <hip/hip_runtime.h>

// ---------------------------------------------------------------------------
// TENProLayer on MI355X — round 4: XOR-swizzled LDS (bank-conflict-free
// fragment reads) + fused h/gate GEMM.
// ---------------------------------------------------------------------------

typedef __bf16 bf16_t;
typedef bf16_t bf16x8 __attribute__((ext_vector_type(8)));
typedef bf16_t bf16x4 __attribute__((ext_vector_type(4)));
typedef float  f32x4  __attribute__((ext_vector_type(4)));

#define Tc   2048
#define Dc   1024
#define BTc  8192     // B*T
#define K2c  128      // 2K
#define MLPc 4096

// ---------------------------------------------------------------------------
// fp32 -> bf16 conversion (9 segments in one launch)
// ---------------------------------------------------------------------------
struct ConvSeg { const float* src; bf16_t* dst; int n; };
struct ConvArgs { ConvSeg s[9]; };

__global__ __launch_bounds__(256) void convert_kernel(ConvArgs a) {
    ConvSeg sg = a.s[blockIdx.y];
    int i = (blockIdx.x * 256 + threadIdx.x) * 4;
    if (i >= sg.n) return;
    float4 v = *(const float4*)(sg.src + i);
    bf16x4 o;
    o[0] = (bf16_t)v.x; o[1] = (bf16_t)v.y; o[2] = (bf16_t)v.z; o[3] = (bf16_t)v.w;
    *(bf16x4*)(sg.dst + i) = o;
}

// ---------------------------------------------------------------------------
// LayerNorm: fp32 in -> bf16 out. One block per row (D=1024).
// ---------------------------------------------------------------------------
__global__ __launch_bounds__(256) void ln_kernel(const float* __restrict__ x,
                                                 const float* __restrict__ g,
                                                 const float* __restrict__ bb,
                                                 bf16_t* __restrict__ out) {
    int row = blockIdx.x;
    int tid = threadIdx.x;
    float4 v = ((const float4*)(x + (size_t)row * Dc))[tid];
    float s  = v.x + v.y + v.z + v.w;
    float ss = v.x * v.x + v.y * v.y + v.z * v.z + v.w * v.w;
#pragma unroll
    for (int d = 32; d > 0; d >>= 1) {
        s  += __shfl_down(s, d);
        ss += __shfl_down(ss, d);
    }
    __shared__ float red[8];
    int wv = tid >> 6;
    if ((tid & 63) == 0) { red[wv] = s; red[4 + wv] = ss; }
    __syncthreads();
    s  = red[0] + red[1] + red[2] + red[3];
    ss = red[4] + red[5] + red[6] + red[7];
    float mean = s * (1.0f / Dc);
    float var  = ss * (1.0f / Dc) - mean * mean;
    float rstd = rsqrtf(var + 1e-5f);
    float4 g4 = ((const float4*)g)[tid];
    float4 b4 = ((const float4*)bb)[tid];
    bf16x4 o;
    o[0] = (bf16_t)((v.x - mean) * rstd * g4.x + b4.x);
    o[1] = (bf16_t)((v.y - mean) * rstd * g4.y + b4.y);
    o[2] = (bf16_t)((v.z - mean) * rstd * g4.z + b4.z);
    o[3] = (bf16_t)((v.w - mean) * rstd * g4.w + b4.w);
    *(bf16x4*)(out + (size_t)row * Dc + tid * 4) = o;
}

// ---------------------------------------------------------------------------
// m97-style tiled GEMM with XOR-swizzled LDS k-chunk layout.
// C[m,n] = sum_k A[m,k]*W[n,k]. 128x128 tile, BK=32, 4 waves x (64x64).
// Swizzle: logical k-chunk kc of row r stored at physical chunk kc^((r>>1)&3).
// Staging lane permutation keeps the global address set identical (coalesced)
// and the LDS destination contiguous (global_load_lds constraint, m104).
// ---------------------------------------------------------------------------
#define BM 128
#define BN 128
#define BK 32

struct EpiParams {
    const float* bias;
    float*       fout;
    const float* fin;
    bf16_t*      bout;
    bf16_t*      q; bf16_t* k; bf16_t* v;
    const bf16_t* a2; const bf16_t* w2;   // fused gate: h = a2 @ w2^T (K=128)
};

#define GLOAD_LDS(g, l)                                                        \
    __builtin_amdgcn_global_load_lds(                                          \
        (const __attribute__((address_space(1))) unsigned int*)(g),            \
        (__attribute__((address_space(3))) unsigned int*)(l), 16, 0, 0)

template <int EPI>
__global__ __launch_bounds__(256) void gemm_tiled(const bf16_t* __restrict__ A,
                                                  const bf16_t* __restrict__ W,
                                                  int M, int N, int K,
                                                  EpiParams ep) {
    __shared__ bf16_t As[BM * BK];
    __shared__ bf16_t Bs[BN * BK];

    int tid = threadIdx.x;
    int wv = tid >> 6, lane = tid & 63;
    int lane16 = lane & 15, quad = lane >> 4;
    int nbn = N / BN;
    int bm = blockIdx.x / nbn, bn = blockIdx.x % nbn;
    int m0 = bm * BM, n0 = bn * BN;
    int wm = (wv >> 1) * 64, wn = (wv & 1) * 64;

    // staging: lane -> (row = lane>>2, swizzled k-chunk)
    int lrow = lane >> 2;
    int lcol = (((lane & 3) ^ ((lrow >> 1) & 3))) * 8;
    const bf16_t* ga = A + (size_t)(m0 + wv * 16 + lrow) * K + lcol;
    const bf16_t* gb = W + (size_t)(n0 + wv * 16 + lrow) * K + lcol;
    size_t gstep64 = (size_t)64 * K;
    bf16_t* la0 = &As[(wv * 16) * BK];
    bf16_t* la1 = &As[(64 + wv * 16) * BK];
    bf16_t* lb0 = &Bs[(wv * 16) * BK];
    bf16_t* lb1 = &Bs[(64 + wv * 16) * BK];

    // fragment-read physical chunk (inverse swizzle)
    int pc = (quad ^ ((lane16 >> 1) & 3)) * 8;

    f32x4 zz = {0.f, 0.f, 0.f, 0.f};
    f32x4 acc[4][4];
#pragma unroll
    for (int mi = 0; mi < 4; mi++)
#pragma unroll
        for (int ni = 0; ni < 4; ni++) acc[mi][ni] = zz;

    for (int k0 = 0; k0 < K; k0 += BK) {
        GLOAD_LDS(ga + k0, la0);
        GLOAD_LDS(ga + k0 + gstep64, la1);
        GLOAD_LDS(gb + k0, lb0);
        GLOAD_LDS(gb + k0 + gstep64, lb1);
        __syncthreads();
        bf16x8 af[4], bfr[4];
#pragma unroll
        for (int mi = 0; mi < 4; mi++)
            af[mi] = *(const bf16x8*)&As[(wm + mi * 16 + lane16) * BK + pc];
#pragma unroll
        for (int ni = 0; ni < 4; ni++)
            bfr[ni] = *(const bf16x8*)&Bs[(wn + ni * 16 + lane16) * BK + pc];
#pragma unroll
        for (int mi = 0; mi < 4; mi++)
#pragma unroll
            for (int ni = 0; ni < 4; ni++)
                acc[mi][ni] = __builtin_amdgcn_mfma_f32_16x16x32_bf16(
                    af[mi], bfr[ni], acc[mi][ni], 0, 0, 0);
        __syncthreads();
    }

    // fused h-phase (EPI==6): second accumulator over K2=128
    f32x4 acc2[4][4];
    if constexpr (EPI == 6) {
#pragma unroll
        for (int mi = 0; mi < 4; mi++)
#pragma unroll
            for (int ni = 0; ni < 4; ni++) acc2[mi][ni] = zz;
        const bf16_t* ga2 = ep.a2 + (size_t)(m0 + wv * 16 + lrow) * K2c + lcol;
        const bf16_t* gb2 = ep.w2 + (size_t)(n0 + wv * 16 + lrow) * K2c + lcol;
        size_t gstep64b = (size_t)64 * K2c;
        for (int k0 = 0; k0 < K2c; k0 += BK) {
            GLOAD_LDS(ga2 + k0, la0);
            GLOAD_LDS(ga2 + k0 + gstep64b, la1);
            GLOAD_LDS(gb2 + k0, lb0);
            GLOAD_LDS(gb2 + k0 + gstep64b, lb1);
            __syncthreads();
            bf16x8 af[4], bfr[4];
#pragma unroll
            for (int mi = 0; mi < 4; mi++)
                af[mi] = *(const bf16x8*)&As[(wm + mi * 16 + lane16) * BK + pc];
#pragma unroll
            for (int ni = 0; ni < 4; ni++)
                bfr[ni] = *(const bf16x8*)&Bs[(wn + ni * 16 + lane16) * BK + pc];
#pragma unroll
            for (int mi = 0; mi < 4; mi++)
#pragma unroll
                for (int ni = 0; ni < 4; ni++)
                    acc2[mi][ni] = __builtin_amdgcn_mfma_f32_16x16x32_bf16(
                        af[mi], bfr[ni], acc2[mi][ni], 0, 0, 0);
            __syncthreads();
        }
    }

#pragma unroll
    for (int mi = 0; mi < 4; mi++)
#pragma unroll
        for (int ni = 0; ni < 4; ni++)
#pragma unroll
            for (int r = 0; r < 4; r++) {
                int row = m0 + wm + mi * 16 + quad * 4 + r;
                int col = n0 + wn + ni * 16 + lane16;
                float v = acc[mi][ni][r];
                if constexpr (EPI == 1) {          // mlp1: silu -> bf16
                    v += ep.bias[col];
                    ep.bout[(size_t)row * N + col] = (bf16_t)(v / (1.0f + __expf(-v)));
                } else if constexpr (EPI == 2) {   // residual + bias -> fp32
                    size_t o = (size_t)row * N + col;
                    ep.fout[o] = ep.fin[o] + v + ep.bias[col];
                } else if constexpr (EPI == 3) {   // q/k: bias + scatter bf16
                    v += ep.bias[col];
                    int part = col >> 10, d1 = col & 1023;
                    int hh = d1 >> 8, hd = d1 & 255;
                    int b = row >> 11, t = row & 2047;
                    bf16_t* dst = (part == 0) ? ep.q : ep.k;
                    dst[(((size_t)(b * 4 + hh) * Tc + t) << 8) + hd] = (bf16_t)v;
                } else if constexpr (EPI == 5) {   // V^T: row=dim, col=bt
                    v += ep.bias[2048 + row];
                    int b = col >> 11, t = col & 2047;
                    int hh = row >> 8, dd = row & 255;
                    ep.v[((size_t)((b * 4 + hh) * 256 + dd)) * Tc + t] = (bf16_t)v;
                } else if constexpr (EPI == 6) {   // fused spectral gate
                    size_t o = (size_t)row * N + col;
                    float g = 1.0f / (1.0f + __expf(-(v + ep.bias[col])));
                    ep.fout[o] = ep.fin[o] + g * acc2[mi][ni][r];
                }
            }
}

// ---------------------------------------------------------------------------
// Small-N GEMM (beta, N=128): 32x32-per-wave direct-load MFMA.
// ---------------------------------------------------------------------------
__device__ __forceinline__ void mm32(const bf16_t* __restrict__ A,
                                     const bf16_t* __restrict__ W,
                                     int K, int m0, int n0,
                                     int lane16, int quad, f32x4 (&acc)[2][2]) {
    const bf16_t* a0 = A + (size_t)(m0 + lane16) * K + quad * 8;
    const bf16_t* a1 = a0 + (size_t)16 * K;
    const bf16_t* w0 = W + (size_t)(n0 + lane16) * K + quad * 8;
    const bf16_t* w1 = w0 + (size_t)16 * K;
#pragma unroll 4
    for (int k = 0; k < K; k += 32) {
        bf16x8 av0 = *(const bf16x8*)(a0 + k);
        bf16x8 av1 = *(const bf16x8*)(a1 + k);
        bf16x8 bv0 = *(const bf16x8*)(w0 + k);
        bf16x8 bv1 = *(const bf16x8*)(w1 + k);
        acc[0][0] = __builtin_amdgcn_mfma_f32_16x16x32_bf16(av0, bv0, acc[0][0], 0, 0, 0);
        acc[0][1] = __builtin_amdgcn_mfma_f32_16x16x32_bf16(av0, bv1, acc[0][1], 0, 0, 0);
        acc[1][0] = __builtin_amdgcn_mfma_f32_16x16x32_bf16(av1, bv0, acc[1][0], 0, 0, 0);
        acc[1][1] = __builtin_amdgcn_mfma_f32_16x16x32_bf16(av1, bv1, acc[1][1], 0, 0, 0);
    }
}

__global__ __launch_bounds__(256) void gemm_beta(const bf16_t* __restrict__ xn,
                                                 const bf16_t* __restrict__ ipw,
                                                 const bf16_t* __restrict__ prevb,
                                                 const bf16_t* __restrict__ mpw,
                                                 const float* __restrict__ mgate_p,
                                                 float* __restrict__ beta_c) {
    int lane = threadIdx.x & 63;
    int wave = threadIdx.x >> 6;
    int gid  = blockIdx.x * 4 + wave;
    int mt = gid / 4, nt = gid % 4;
    int m0 = mt * 32, n0 = nt * 32;
    int lane16 = lane & 15, quad = lane >> 4;
    f32x4 zz = {0.f, 0.f, 0.f, 0.f};
    f32x4 acc[2][2] = {{zz, zz}, {zz, zz}};
    mm32(xn, ipw, Dc, m0, n0, lane16, quad, acc);
    f32x4 acc2[2][2] = {{zz, zz}, {zz, zz}};
    mm32(prevb, mpw, K2c, m0, n0, lane16, quad, acc2);
    float mg = 1.0f / (1.0f + __expf(-mgate_p[0]));
    for (int mi = 0; mi < 2; mi++)
        for (int ni = 0; ni < 2; ni++)
            for (int r = 0; r < 4; r++) {
                int row = m0 + mi * 16 + quad * 4 + r;
                int col = n0 + ni * 16 + lane16;
                int b = row >> 11, t = row & 2047;
                beta_c[((size_t)b * K2c + col) * Tc + t] =
                    acc[mi][ni][r] + mg * acc2[mi][ni][r];
            }
}

// ---------------------------------------------------------------------------
// Complex diagonal SSM scan (wave-parallel Kogge-Stone, 32 steps/lane).
// ---------------------------------------------------------------------------
__global__ __launch_bounds__(64) void scan_kernel(const float* __restrict__ beta_c,
                                                  const float* __restrict__ log_decay,
                                                  const float* __restrict__ freq,
                                                  float* __restrict__ cbuf) {
    int b = blockIdx.x >> 6;
    int k = blockIdx.x & 63;
    int lane = threadIdx.x;
    float lam = expf(log_decay[k]);
    float fr = freq[k];
    float lr = lam * cosf(fr), li = lam * sinf(fr);

    const float* br_p = beta_c + ((size_t)b * K2c + k) * Tc + lane * 32;
    const float* bi_p = beta_c + ((size_t)b * K2c + 64 + k) * Tc + lane * 32;
    float br[32], bi[32];
#pragma unroll
    for (int i = 0; i < 8; i++) {
        *(float4*)(&br[i * 4]) = ((const float4*)br_p)[i];
        *(float4*)(&bi[i * 4]) = ((const float4*)bi_p)[i];
    }
    float sr = 0.f, si = 0.f;
#pragma unroll
    for (int i = 0; i < 32; i++) {
        float nr = lr * sr - li * si + br[i];
        float ni = lr * si + li * sr + bi[i];
        sr = nr; si = ni;
    }
    float Mr = lr, Mi = li;
#pragma unroll
    for (int i = 0; i < 5; i++) {
        float nr = Mr * Mr - Mi * Mi, ni = 2.f * Mr * Mi;
        Mr = nr; Mi = ni;
    }
    float ir = sr, ii = si;
#pragma unroll
    for (int d = 1; d < 64; d <<= 1) {
        float pr = __shfl_up(ir, d);
        float pi = __shfl_up(ii, d);
        if (lane >= d) {
            ir += Mr * pr - Mi * pi;
            ii += Mr * pi + Mi * pr;
        }
        float nr = Mr * Mr - Mi * Mi, ni = 2.f * Mr * Mi;
        Mr = nr; Mi = ni;
    }
    float cr = __shfl_up(ir, 1), ci = __shfl_up(ii, 1);
    if (lane == 0) { cr = 0.f; ci = 0.f; }
    float* cr_p = cbuf + ((size_t)b * K2c + k) * Tc + lane * 32;
    float* ci_p = cbuf + ((size_t)b * K2c + 64 + k) * Tc + lane * 32;
    sr = cr; si = ci;
#pragma unroll
    for (int i = 0; i < 32; i++) {
        float nr = lr * sr - li * si + br[i];
        float ni = lr * si + li * sr + bi[i];
        sr = nr; si = ni;
        cr_p[i] = sr; ci_p[i] = si;
    }
}

// ---------------------------------------------------------------------------
// Per-head coupling + concat -> eigenstates (fp32 output #2 + bf16 copy)
// ---------------------------------------------------------------------------
__global__ __launch_bounds__(256) void coupling_kernel(const float* __restrict__ cbuf,
                                                       const float* __restrict__ cpl,
                                                       float* __restrict__ eig_out,
                                                       bf16_t* __restrict__ eigb) {
    int idx = blockIdx.x * 256 + threadIdx.x;
    int col = idx & 127;
    int t = (idx >> 7) & 2047;
    int b = idx >> 18;
    int ri = col >> 6, hj = col & 63, h2 = hj >> 4, j = hj & 15;
    const float* crow = cbuf + ((size_t)b * K2c + ri * 64 + h2 * 16) * Tc + t;
    const float* cw = cpl + (h2 * 16 + j) * 16;
    float acc = 0.f;
#pragma unroll
    for (int kk = 0; kk < 16; kk++) acc += cw[kk] * crow[(size_t)kk * Tc];
    eig_out[idx] = acc;
    eigb[idx] = (bf16_t)acc;
}

// ---------------------------------------------------------------------------
// MFMA sliding-window attention. Wave = 16 queries, key span 144 (9 tiles).
// ---------------------------------------------------------------------------
#define LDP 168

__global__ __launch_bounds__(256) void attn_mfma(const bf16_t* __restrict__ qb,
                                                 const bf16_t* __restrict__ kb,
                                                 const bf16_t* __restrict__ vt,
                                                 bf16_t* __restrict__ ao) {
    __shared__ bf16_t Pl[4 * 16 * LDP];
    int tid = threadIdx.x;
    int wv = tid >> 6, lane = tid & 63;
    int lane16 = lane & 15, quad = lane >> 4;
    int qblk = blockIdx.x & 31;
    int bh = blockIdx.x >> 5;
    int qw0 = qblk * 64 + wv * 16;
    const bf16_t* qp = qb + (size_t)bh * Tc * 256;
    const bf16_t* kp = kb + (size_t)bh * Tc * 256;
    const bf16_t* vp = vt + (size_t)bh * 256 * Tc;
    bf16_t* Pw = &Pl[wv * 16 * LDP];

    for (int i = lane; i < 16 * 24; i += 64) {
        int r = i / 24, c = 144 + (i % 24);
        Pw[r * LDP + c] = (bf16_t)0.f;
    }

    bf16x8 qf[8];
#pragma unroll
    for (int ks = 0; ks < 8; ks++)
        qf[ks] = *(const bf16x8*)(qp + (size_t)(qw0 + lane16) * 256 + ks * 32 + quad * 8);

    f32x4 zz = {0.f, 0.f, 0.f, 0.f};
    f32x4 S[9];
#pragma unroll
    for (int jt = 0; jt < 9; jt++) S[jt] = zz;
    int kbase = qw0 - 128;

#pragma unroll
    for (int ks = 0; ks < 8; ks++) {
        bf16x8 kf[9];
#pragma unroll
        for (int jt = 0; jt < 9; jt++) {
            int krow = kbase + jt * 16 + lane16;
            krow = krow < 0 ? 0 : krow;
            kf[jt] = *(const bf16x8*)(kp + (size_t)krow * 256 + ks * 32 + quad * 8);
        }
#pragma unroll
        for (int jt = 0; jt < 9; jt++)
            S[jt] = __builtin_amdgcn_mfma_f32_16x16x32_bf16(qf[ks], kf[jt], S[jt], 0, 0, 0);
    }

    float m[4], l[4];
#pragma unroll
    for (int r = 0; r < 4; r++) m[r] = -1e30f;
#pragma unroll
    for (int jt = 0; jt < 9; jt++) {
        int kg = kbase + jt * 16 + lane16;
#pragma unroll
        for (int r = 0; r < 4; r++) {
            int qrow = qw0 + quad * 4 + r;
            bool ok = (kg >= 0) && (kg <= qrow) && (kg >= qrow - 128);
            float v = ok ? S[jt][r] * 0.0625f : -1e30f;
            S[jt][r] = v;
            m[r] = fmaxf(m[r], v);
        }
    }
#pragma unroll
    for (int d = 1; d < 16; d <<= 1)
#pragma unroll
        for (int r = 0; r < 4; r++)
            m[r] = fmaxf(m[r], __shfl_xor(m[r], d));
#pragma unroll
    for (int r = 0; r < 4; r++) l[r] = 0.f;
#pragma unroll
    for (int jt = 0; jt < 9; jt++)
#pragma unroll
        for (int r = 0; r < 4; r++) {
            float p = __expf(S[jt][r] - m[r]);
            S[jt][r] = p;
            l[r] += p;
        }
#pragma unroll
    for (int d = 1; d < 16; d <<= 1)
#pragma unroll
        for (int r = 0; r < 4; r++)
            l[r] += __shfl_xor(l[r], d);

#pragma unroll
    for (int jt = 0; jt < 9; jt++)
#pragma unroll
        for (int r = 0; r < 4; r++)
            Pw[(quad * 4 + r) * LDP + jt * 16 + lane16] = (bf16_t)S[jt][r];
    __syncthreads();

    f32x4 O[16];
#pragma unroll
    for (int nt = 0; nt < 16; nt++) O[nt] = zz;
#pragma unroll
    for (int ks = 0; ks < 5; ks++) {
        bf16x8 pf = *(const bf16x8*)&Pw[lane16 * LDP + ks * 32 + quad * 8];
        int kidx = kbase + ks * 32 + quad * 8;
        kidx = kidx < 0 ? 0 : kidx;
        kidx = kidx > (Tc - 8) ? (Tc - 8) : kidx;
#pragma unroll
        for (int nt = 0; nt < 16; nt++) {
            bf16x8 vf = *(const bf16x8*)(vp + (size_t)(nt * 16 + lane16) * Tc + kidx);
            O[nt] = __builtin_amdgcn_mfma_f32_16x16x32_bf16(pf, vf, O[nt], 0, 0, 0);
        }
    }

    float rl[4];
#pragma unroll
    for (int r = 0; r < 4; r++) rl[r] = 1.0f / l[r];
    int b = bh >> 2, h = bh & 3;
#pragma unroll
    for (int nt = 0; nt < 16; nt++)
#pragma unroll
        for (int r = 0; r < 4; r++) {
            int qrow = qw0 + quad * 4 + r;
            int dim = nt * 16 + lane16;
            ao[((size_t)(b * Tc + qrow)) * Dc + h * 256 + dim] = (bf16_t)(O[nt][r] * rl[r]);
        }
}

// ---------------------------------------------------------------------------
// Launch
// ---------------------------------------------------------------------------
extern "C" void kernel_launch(void* const* d_in, const int* in_sizes, int n_in,
                              void* d_out, int out_size, void* d_ws, size_t ws_size,
                              hipStream_t stream) {
    const float* x            = (const float*)d_in[0];
    const float* prev_eig     = (const float*)d_in[1];
    const float* norm1_g      = (const float*)d_in[2];
    const float* norm1_b      = (const float*)d_in[3];
    const float* in_proj_w    = (const float*)d_in[4];
    const float* memory_gate  = (const float*)d_in[5];
    const float* memory_proj_w= (const float*)d_in[6];
    const float* log_decay    = (const float*)d_in[7];
    const float* frequency    = (const float*)d_in[8];
    const float* coupling     = (const float*)d_in[9];
    const float* main_gate_w  = (const float*)d_in[10];
    const float* main_gate_b  = (const float*)d_in[11];
    const float* out_proj_w   = (const float*)d_in[12];
    const float* attn_norm_g  = (const float*)d_in[13];
    const float* attn_norm_b  = (const float*)d_in[14];
    const float* attn_in_w    = (const float*)d_in[15];
    const float* attn_in_b    = (const float*)d_in[16];
    const float* attn_out_w   = (const float*)d_in[17];
    const float* attn_out_b   = (const float*)d_in[18];
    const float* norm2_g      = (const float*)d_in[19];
    const float* norm2_b      = (const float*)d_in[20];
    const float* mlp_w1       = (const float*)d_in[21];
    const float* mlp_b1       = (const float*)d_in[22];
    const float* mlp_w2       = (const float*)d_in[23];
    const float* mlp_b2       = (const float*)d_in[24];

    char* ws = (char*)d_ws;
    bf16_t* ipw_b  = (bf16_t*)(ws + 0);
    bf16_t* mpw_b  = (bf16_t*)(ws + 262144);
    bf16_t* mgw_b  = (bf16_t*)(ws + 294912);
    bf16_t* opw_b  = (bf16_t*)(ws + 2392064);
    bf16_t* aiw_b  = (bf16_t*)(ws + 2654208);
    bf16_t* aow_b  = (bf16_t*)(ws + 8945664);
    bf16_t* w1_b   = (bf16_t*)(ws + 11042816);
    bf16_t* w2_b   = (bf16_t*)(ws + 19431424);
    bf16_t* prev_b = (bf16_t*)(ws + 27820032);
    const size_t OFF_ACTA = 29917184;
    const size_t OFF_BIG  = OFF_ACTA + 16777216;
    bf16_t* actA   = (bf16_t*)(ws + OFF_ACTA);
    float*  beta_c = (float*)(ws + OFF_BIG);
    float*  cbuf   = (float*)(ws + OFF_BIG + 4194304);
    bf16_t* eigb   = (bf16_t*)(ws + OFF_BIG + 8388608);
    bf16_t* qbuf   = (bf16_t*)(ws + OFF_BIG);
    bf16_t* kbuf   = (bf16_t*)(ws + OFF_BIG + 16777216);
    bf16_t* vtbuf  = (bf16_t*)(ws + OFF_BIG + 33554432);       // (b,h,d,t)
    bf16_t* mbuf   = (bf16_t*)(ws + OFF_BIG);

    float* out_x   = (float*)d_out;
    float* out_eig = out_x + (size_t)BTc * Dc;
    float* xres    = out_x;

    ConvArgs ca;
    ca.s[0] = ConvSeg{in_proj_w,     ipw_b,  131072};
    ca.s[1] = ConvSeg{memory_proj_w, mpw_b,  16384};
    ca.s[2] = ConvSeg{main_gate_w,   mgw_b,  1048576};
    ca.s[3] = ConvSeg{out_proj_w,    opw_b,  131072};
    ca.s[4] = ConvSeg{attn_in_w,     aiw_b,  3145728};
    ca.s[5] = ConvSeg{attn_out_w,    aow_b,  1048576};
    ca.s[6] = ConvSeg{mlp_w1,        w1_b,   4194304};
    ca.s[7] = ConvSeg{mlp_w2,        w2_b,   4194304};
    ca.s[8] = ConvSeg{prev_eig,      prev_b, 1048576};
    convert_kernel<<<dim3(4096, 9), 256, 0, stream>>>(ca);

    EpiParams ep{};

    ln_kernel<<<BTc, 256, 0, stream>>>(x, norm1_g, norm1_b, actA);
    gemm_beta<<<256, 256, 0, stream>>>(actA, ipw_b, prev_b, mpw_b, memory_gate, beta_c);
    scan_kernel<<<256, 64, 0, stream>>>(beta_c, log_decay, frequency, cbuf);
    coupling_kernel<<<4096, 256, 0, stream>>>(cbuf, coupling, out_eig, eigb);
    // x1 = x + sigmoid(xn@mgw^T + mgb) * (eig@opw^T)   [fused dual-K]
    ep = EpiParams{}; ep.bias = main_gate_b; ep.fin = x; ep.fout = xres;
    ep.a2 = eigb; ep.w2 = opw_b;
    gemm_tiled<6><<<(BTc/BM)*(Dc/BN), 256, 0, stream>>>(actA, mgw_b, BTc, Dc, Dc, ep);
    ln_kernel<<<BTc, 256, 0, stream>>>(xres, attn_norm_g, attn_norm_b, actA);
    // q,k (N=2048)
    ep = EpiParams{}; ep.bias = attn_in_b; ep.q = qbuf; ep.k = kbuf;
    gemm_tiled<3><<<(BTc/BM)*(2048/BN), 256, 0, stream>>>(actA, aiw_b, BTc, 2048, Dc, ep);
    // V^T (M=1024 dims, N=8192 tokens)
    ep = EpiParams{}; ep.bias = attn_in_b; ep.v = vtbuf;
    gemm_tiled<5><<<(Dc/BM)*(BTc/BN), 256, 0, stream>>>(aiw_b + (size_t)2048 * Dc, actA,
                                                        Dc, BTc, Dc, ep);
    // attention -> ao (reuses actA)
    attn_mfma<<<512, 256, 0, stream>>>(qbuf, kbuf, vtbuf, actA);
    // x2 = x1 + ao@aow^T + aob
    ep = EpiParams{}; ep.bias = attn_out_b; ep.fin = xres; ep.fout = xres;
    gemm_tiled<2><<<(BTc/BM)*(Dc/BN), 256, 0, stream>>>(actA, aow_b, BTc, Dc, Dc, ep);
    ln_kernel<<<BTc, 256, 0, stream>>>(xres, norm2_g, norm2_b, actA);
    // mlp1 (silu)
    ep = EpiParams{}; ep.bias = mlp_b1; ep.bout = mbuf;
    gemm_tiled<1><<<(BTc/BM)*(MLPc/BN), 256, 0, stream>>>(actA, w1_b, BTc, MLPc, Dc, ep);
    // mlp2 + residual
    ep = EpiParams{}; ep.bias = mlp_b2; ep.fin = xres; ep.fout = out_x;
    gemm_tiled<2><<<(BTc/BM)*(Dc/BN), 256, 0, stream>>>(mbuf, w2_b, BTc, Dc, MLPc, ep);

    (void)in_sizes; (void)n_in; (void)out_size; (void)ws_size;
}

// Round 5
// 640.744 us; speedup vs baseline: 1.0912x; 1.0912x over previous
//
#include <hip/hip_runtime.h>

// ---------------------------------------------------------------------------
// TENProLayer on MI355X — round 5: XCD-stripe block scheduling (L2 reuse of
// A-tiles) + BK=64 K-loop (half the barriers), XOR-swizzled LDS.
// ---------------------------------------------------------------------------

typedef __bf16 bf16_t;
typedef bf16_t bf16x8 __attribute__((ext_vector_type(8)));
typedef bf16_t bf16x4 __attribute__((ext_vector_type(4)));
typedef float  f32x4  __attribute__((ext_vector_type(4)));

#define Tc   2048
#define Dc   1024
#define BTc  8192     // B*T
#define K2c  128      // 2K
#define MLPc 4096

// ---------------------------------------------------------------------------
// fp32 -> bf16 conversion (9 segments in one launch)
// ---------------------------------------------------------------------------
struct ConvSeg { const float* src; bf16_t* dst; int n; };
struct ConvArgs { ConvSeg s[9]; };

__global__ __launch_bounds__(256) void convert_kernel(ConvArgs a) {
    ConvSeg sg = a.s[blockIdx.y];
    int i = (blockIdx.x * 256 + threadIdx.x) * 4;
    if (i >= sg.n) return;
    float4 v = *(const float4*)(sg.src + i);
    bf16x4 o;
    o[0] = (bf16_t)v.x; o[1] = (bf16_t)v.y; o[2] = (bf16_t)v.z; o[3] = (bf16_t)v.w;
    *(bf16x4*)(sg.dst + i) = o;
}

// ---------------------------------------------------------------------------
// LayerNorm: fp32 in -> bf16 out. One block per row (D=1024).
// ---------------------------------------------------------------------------
__global__ __launch_bounds__(256) void ln_kernel(const float* __restrict__ x,
                                                 const float* __restrict__ g,
                                                 const float* __restrict__ bb,
                                                 bf16_t* __restrict__ out) {
    int row = blockIdx.x;
    int tid = threadIdx.x;
    float4 v = ((const float4*)(x + (size_t)row * Dc))[tid];
    float s  = v.x + v.y + v.z + v.w;
    float ss = v.x * v.x + v.y * v.y + v.z * v.z + v.w * v.w;
#pragma unroll
    for (int d = 32; d > 0; d >>= 1) {
        s  += __shfl_down(s, d);
        ss += __shfl_down(ss, d);
    }
    __shared__ float red[8];
    int wv = tid >> 6;
    if ((tid & 63) == 0) { red[wv] = s; red[4 + wv] = ss; }
    __syncthreads();
    s  = red[0] + red[1] + red[2] + red[3];
    ss = red[4] + red[5] + red[6] + red[7];
    float mean = s * (1.0f / Dc);
    float var  = ss * (1.0f / Dc) - mean * mean;
    float rstd = rsqrtf(var + 1e-5f);
    float4 g4 = ((const float4*)g)[tid];
    float4 b4 = ((const float4*)bb)[tid];
    bf16x4 o;
    o[0] = (bf16_t)((v.x - mean) * rstd * g4.x + b4.x);
    o[1] = (bf16_t)((v.y - mean) * rstd * g4.y + b4.y);
    o[2] = (bf16_t)((v.z - mean) * rstd * g4.z + b4.z);
    o[3] = (bf16_t)((v.w - mean) * rstd * g4.w + b4.w);
    *(bf16x4*)(out + (size_t)row * Dc + tid * 4) = o;
}

// ---------------------------------------------------------------------------
// Tiled GEMM: C[m,n] = sum_k A[m,k]*W[n,k]. 128x128 tile, BK=64, 4 waves.
// XCD-stripe scheduling: blocks sharing A-rows run on one XCD (L2 reuse).
// XOR-swizzled LDS chunks: phys = logical ^ (row&7) -> conflict-free reads.
// ---------------------------------------------------------------------------
#define BM 128
#define BN 128
#define BKT 64

struct EpiParams {
    const float* bias;
    float*       fout;
    const float* fin;
    bf16_t*      bout;
    bf16_t*      q; bf16_t* k; bf16_t* v;
    const bf16_t* a2; const bf16_t* w2;   // fused gate: h = a2 @ w2^T (K=128)
};

#define GLOAD_LDS(g, l)                                                        \
    __builtin_amdgcn_global_load_lds(                                          \
        (const __attribute__((address_space(1))) unsigned int*)(g),            \
        (__attribute__((address_space(3))) unsigned int*)(l), 16, 0, 0)

template <int EPI>
__global__ __launch_bounds__(256) void gemm_tiled(const bf16_t* __restrict__ A,
                                                  const bf16_t* __restrict__ W,
                                                  int M, int N, int K,
                                                  EpiParams ep) {
    __shared__ bf16_t As[BM * BKT];
    __shared__ bf16_t Bs[BN * BKT];

    int tid = threadIdx.x;
    int wv = tid >> 6, lane = tid & 63;
    int lane16 = lane & 15, quad = lane >> 4;
    int nbn = N / BN, nbm = M / BM;

    // XCD-stripe remap: xcd = bid&7 owns bm in [xcd*bm_per, (xcd+1)*bm_per)
    int bid = blockIdx.x;
    int xcd = bid & 7;
    int slot = bid >> 3;
    int bm_per = nbm >> 3;
    int bmo = slot / nbn;
    int bno = slot % nbn;
    if (bmo & 1) bno = nbn - 1 - bno;     // serpentine for B-tile reuse
    int bm = xcd * bm_per + bmo, bn = bno;
    int m0 = bm * BM, n0 = bn * BN;
    int wm = (wv >> 1) * 64, wn = (wv & 1) * 64;

    // staging: each load = 64 lanes x 16B = 8 rows x 128B. lane -> (row, chunk)
    int lrow = lane >> 3;                       // 0..7
    int lcol = ((lane & 7) ^ lrow) * 8;         // swizzled global chunk
    const bf16_t* ga = A + (size_t)(m0 + wv * 32 + lrow) * K + lcol;
    const bf16_t* gb = W + (size_t)(n0 + wv * 32 + lrow) * K + lcol;

    f32x4 zz = {0.f, 0.f, 0.f, 0.f};
    f32x4 acc[4][4];
#pragma unroll
    for (int mi = 0; mi < 4; mi++)
#pragma unroll
        for (int ni = 0; ni < 4; ni++) acc[mi][ni] = zz;

    for (int k0 = 0; k0 < K; k0 += BKT) {
#pragma unroll
        for (int j = 0; j < 4; j++) {
            GLOAD_LDS(ga + k0 + (size_t)(j * 8) * K, &As[(wv * 32 + j * 8) * BKT]);
            GLOAD_LDS(gb + k0 + (size_t)(j * 8) * K, &Bs[(wv * 32 + j * 8) * BKT]);
        }
        __syncthreads();
#pragma unroll
        for (int ks = 0; ks < 2; ks++) {
            bf16x8 af[4], bfr[4];
#pragma unroll
            for (int mi = 0; mi < 4; mi++)
                af[mi] = *(const bf16x8*)&As[(wm + mi * 16 + lane16) * BKT +
                                             (((ks * 4 + quad) ^ (lane16 & 7)) * 8)];
#pragma unroll
            for (int ni = 0; ni < 4; ni++)
                bfr[ni] = *(const bf16x8*)&Bs[(wn + ni * 16 + lane16) * BKT +
                                              (((ks * 4 + quad) ^ (lane16 & 7)) * 8)];
#pragma unroll
            for (int mi = 0; mi < 4; mi++)
#pragma unroll
                for (int ni = 0; ni < 4; ni++)
                    acc[mi][ni] = __builtin_amdgcn_mfma_f32_16x16x32_bf16(
                        af[mi], bfr[ni], acc[mi][ni], 0, 0, 0);
        }
        __syncthreads();
    }

    // fused h-phase (EPI==6): second accumulator over K2=128
    f32x4 acc2[4][4];
    if constexpr (EPI == 6) {
#pragma unroll
        for (int mi = 0; mi < 4; mi++)
#pragma unroll
            for (int ni = 0; ni < 4; ni++) acc2[mi][ni] = zz;
        const bf16_t* ga2 = ep.a2 + (size_t)(m0 + wv * 32 + lrow) * K2c + lcol;
        const bf16_t* gb2 = ep.w2 + (size_t)(n0 + wv * 32 + lrow) * K2c + lcol;
        for (int k0 = 0; k0 < K2c; k0 += BKT) {
#pragma unroll
            for (int j = 0; j < 4; j++) {
                GLOAD_LDS(ga2 + k0 + (size_t)(j * 8) * K2c, &As[(wv * 32 + j * 8) * BKT]);
                GLOAD_LDS(gb2 + k0 + (size_t)(j * 8) * K2c, &Bs[(wv * 32 + j * 8) * BKT]);
            }
            __syncthreads();
#pragma unroll
            for (int ks = 0; ks < 2; ks++) {
                bf16x8 af[4], bfr[4];
#pragma unroll
                for (int mi = 0; mi < 4; mi++)
                    af[mi] = *(const bf16x8*)&As[(wm + mi * 16 + lane16) * BKT +
                                                 (((ks * 4 + quad) ^ (lane16 & 7)) * 8)];
#pragma unroll
                for (int ni = 0; ni < 4; ni++)
                    bfr[ni] = *(const bf16x8*)&Bs[(wn + ni * 16 + lane16) * BKT +
                                                  (((ks * 4 + quad) ^ (lane16 & 7)) * 8)];
#pragma unroll
                for (int mi = 0; mi < 4; mi++)
#pragma unroll
                    for (int ni = 0; ni < 4; ni++)
                        acc2[mi][ni] = __builtin_amdgcn_mfma_f32_16x16x32_bf16(
                            af[mi], bfr[ni], acc2[mi][ni], 0, 0, 0);
            }
            __syncthreads();
        }
    }

#pragma unroll
    for (int mi = 0; mi < 4; mi++)
#pragma unroll
        for (int ni = 0; ni < 4; ni++)
#pragma unroll
            for (int r = 0; r < 4; r++) {
                int row = m0 + wm + mi * 16 + quad * 4 + r;
                int col = n0 + wn + ni * 16 + lane16;
                float v = acc[mi][ni][r];
                if constexpr (EPI == 1) {          // mlp1: silu -> bf16
                    v += ep.bias[col];
                    ep.bout[(size_t)row * N + col] = (bf16_t)(v / (1.0f + __expf(-v)));
                } else if constexpr (EPI == 2) {   // residual + bias -> fp32
                    size_t o = (size_t)row * N + col;
                    ep.fout[o] = ep.fin[o] + v + ep.bias[col];
                } else if constexpr (EPI == 3) {   // q/k: bias + scatter bf16
                    v += ep.bias[col];
                    int part = col >> 10, d1 = col & 1023;
                    int hh = d1 >> 8, hd = d1 & 255;
                    int b = row >> 11, t = row & 2047;
                    bf16_t* dst = (part == 0) ? ep.q : ep.k;
                    dst[(((size_t)(b * 4 + hh) * Tc + t) << 8) + hd] = (bf16_t)v;
                } else if constexpr (EPI == 5) {   // V^T: row=dim, col=bt
                    v += ep.bias[2048 + row];
                    int b = col >> 11, t = col & 2047;
                    int hh = row >> 8, dd = row & 255;
                    ep.v[((size_t)((b * 4 + hh) * 256 + dd)) * Tc + t] = (bf16_t)v;
                } else if constexpr (EPI == 6) {   // fused spectral gate
                    size_t o = (size_t)row * N + col;
                    float g = 1.0f / (1.0f + __expf(-(v + ep.bias[col])));
                    ep.fout[o] = ep.fin[o] + g * acc2[mi][ni][r];
                }
            }
}

// ---------------------------------------------------------------------------
// Small-N GEMM (beta, N=128): 32x32-per-wave direct-load MFMA.
// ---------------------------------------------------------------------------
__device__ __forceinline__ void mm32(const bf16_t* __restrict__ A,
                                     const bf16_t* __restrict__ W,
                                     int K, int m0, int n0,
                                     int lane16, int quad, f32x4 (&acc)[2][2]) {
    const bf16_t* a0 = A + (size_t)(m0 + lane16) * K + quad * 8;
    const bf16_t* a1 = a0 + (size_t)16 * K;
    const bf16_t* w0 = W + (size_t)(n0 + lane16) * K + quad * 8;
    const bf16_t* w1 = w0 + (size_t)16 * K;
#pragma unroll 4
    for (int k = 0; k < K; k += 32) {
        bf16x8 av0 = *(const bf16x8*)(a0 + k);
        bf16x8 av1 = *(const bf16x8*)(a1 + k);
        bf16x8 bv0 = *(const bf16x8*)(w0 + k);
        bf16x8 bv1 = *(const bf16x8*)(w1 + k);
        acc[0][0] = __builtin_amdgcn_mfma_f32_16x16x32_bf16(av0, bv0, acc[0][0], 0, 0, 0);
        acc[0][1] = __builtin_amdgcn_mfma_f32_16x16x32_bf16(av0, bv1, acc[0][1], 0, 0, 0);
        acc[1][0] = __builtin_amdgcn_mfma_f32_16x16x32_bf16(av1, bv0, acc[1][0], 0, 0, 0);
        acc[1][1] = __builtin_amdgcn_mfma_f32_16x16x32_bf16(av1, bv1, acc[1][1], 0, 0, 0);
    }
}

__global__ __launch_bounds__(256) void gemm_beta(const bf16_t* __restrict__ xn,
                                                 const bf16_t* __restrict__ ipw,
                                                 const bf16_t* __restrict__ prevb,
                                                 const bf16_t* __restrict__ mpw,
                                                 const float* __restrict__ mgate_p,
                                                 float* __restrict__ beta_c) {
    int lane = threadIdx.x & 63;
    int wave = threadIdx.x >> 6;
    int gid  = blockIdx.x * 4 + wave;
    int mt = gid / 4, nt = gid % 4;
    int m0 = mt * 32, n0 = nt * 32;
    int lane16 = lane & 15, quad = lane >> 4;
    f32x4 zz = {0.f, 0.f, 0.f, 0.f};
    f32x4 acc[2][2] = {{zz, zz}, {zz, zz}};
    mm32(xn, ipw, Dc, m0, n0, lane16, quad, acc);
    f32x4 acc2[2][2] = {{zz, zz}, {zz, zz}};
    mm32(prevb, mpw, K2c, m0, n0, lane16, quad, acc2);
    float mg = 1.0f / (1.0f + __expf(-mgate_p[0]));
    for (int mi = 0; mi < 2; mi++)
        for (int ni = 0; ni < 2; ni++)
            for (int r = 0; r < 4; r++) {
                int row = m0 + mi * 16 + quad * 4 + r;
                int col = n0 + ni * 16 + lane16;
                int b = row >> 11, t = row & 2047;
                beta_c[((size_t)b * K2c + col) * Tc + t] =
                    acc[mi][ni][r] + mg * acc2[mi][ni][r];
            }
}

// ---------------------------------------------------------------------------
// Complex diagonal SSM scan (wave-parallel Kogge-Stone, 32 steps/lane).
// ---------------------------------------------------------------------------
__global__ __launch_bounds__(64) void scan_kernel(const float* __restrict__ beta_c,
                                                  const float* __restrict__ log_decay,
                                                  const float* __restrict__ freq,
                                                  float* __restrict__ cbuf) {
    int b = blockIdx.x >> 6;
    int k = blockIdx.x & 63;
    int lane = threadIdx.x;
    float lam = expf(log_decay[k]);
    float fr = freq[k];
    float lr = lam * cosf(fr), li = lam * sinf(fr);

    const float* br_p = beta_c + ((size_t)b * K2c + k) * Tc + lane * 32;
    const float* bi_p = beta_c + ((size_t)b * K2c + 64 + k) * Tc + lane * 32;
    float br[32], bi[32];
#pragma unroll
    for (int i = 0; i < 8; i++) {
        *(float4*)(&br[i * 4]) = ((const float4*)br_p)[i];
        *(float4*)(&bi[i * 4]) = ((const float4*)bi_p)[i];
    }
    float sr = 0.f, si = 0.f;
#pragma unroll
    for (int i = 0; i < 32; i++) {
        float nr = lr * sr - li * si + br[i];
        float ni = lr * si + li * sr + bi[i];
        sr = nr; si = ni;
    }
    float Mr = lr, Mi = li;
#pragma unroll
    for (int i = 0; i < 5; i++) {
        float nr = Mr * Mr - Mi * Mi, ni = 2.f * Mr * Mi;
        Mr = nr; Mi = ni;
    }
    float ir = sr, ii = si;
#pragma unroll
    for (int d = 1; d < 64; d <<= 1) {
        float pr = __shfl_up(ir, d);
        float pi = __shfl_up(ii, d);
        if (lane >= d) {
            ir += Mr * pr - Mi * pi;
            ii += Mr * pi + Mi * pr;
        }
        float nr = Mr * Mr - Mi * Mi, ni = 2.f * Mr * Mi;
        Mr = nr; Mi = ni;
    }
    float cr = __shfl_up(ir, 1), ci = __shfl_up(ii, 1);
    if (lane == 0) { cr = 0.f; ci = 0.f; }
    float* cr_p = cbuf + ((size_t)b * K2c + k) * Tc + lane * 32;
    float* ci_p = cbuf + ((size_t)b * K2c + 64 + k) * Tc + lane * 32;
    sr = cr; si = ci;
#pragma unroll
    for (int i = 0; i < 32; i++) {
        float nr = lr * sr - li * si + br[i];
        float ni = lr * si + li * sr + bi[i];
        sr = nr; si = ni;
        cr_p[i] = sr; ci_p[i] = si;
    }
}

// ---------------------------------------------------------------------------
// Per-head coupling + concat -> eigenstates (fp32 output #2 + bf16 copy)
// ---------------------------------------------------------------------------
__global__ __launch_bounds__(256) void coupling_kernel(const float* __restrict__ cbuf,
                                                       const float* __restrict__ cpl,
                                                       float* __restrict__ eig_out,
                                                       bf16_t* __restrict__ eigb) {
    int idx = blockIdx.x * 256 + threadIdx.x;
    int col = idx & 127;
    int t = (idx >> 7) & 2047;
    int b = idx >> 18;
    int ri = col >> 6, hj = col & 63, h2 = hj >> 4, j = hj & 15;
    const float* crow = cbuf + ((size_t)b * K2c + ri * 64 + h2 * 16) * Tc + t;
    const float* cw = cpl + (h2 * 16 + j) * 16;
    float acc = 0.f;
#pragma unroll
    for (int kk = 0; kk < 16; kk++) acc += cw[kk] * crow[(size_t)kk * Tc];
    eig_out[idx] = acc;
    eigb[idx] = (bf16_t)acc;
}

// ---------------------------------------------------------------------------
// MFMA sliding-window attention. Wave = 16 queries, key span 144 (9 tiles).
// ---------------------------------------------------------------------------
#define LDP 168

__global__ __launch_bounds__(256) void attn_mfma(const bf16_t* __restrict__ qb,
                                                 const bf16_t* __restrict__ kb,
                                                 const bf16_t* __restrict__ vt,
                                                 bf16_t* __restrict__ ao) {
    __shared__ bf16_t Pl[4 * 16 * LDP];
    int tid = threadIdx.x;
    int wv = tid >> 6, lane = tid & 63;
    int lane16 = lane & 15, quad = lane >> 4;
    int qblk = blockIdx.x & 31;
    int bh = blockIdx.x >> 5;
    int qw0 = qblk * 64 + wv * 16;
    const bf16_t* qp = qb + (size_t)bh * Tc * 256;
    const bf16_t* kp = kb + (size_t)bh * Tc * 256;
    const bf16_t* vp = vt + (size_t)bh * 256 * Tc;
    bf16_t* Pw = &Pl[wv * 16 * LDP];

    for (int i = lane; i < 16 * 24; i += 64) {
        int r = i / 24, c = 144 + (i % 24);
        Pw[r * LDP + c] = (bf16_t)0.f;
    }

    bf16x8 qf[8];
#pragma unroll
    for (int ks = 0; ks < 8; ks++)
        qf[ks] = *(const bf16x8*)(qp + (size_t)(qw0 + lane16) * 256 + ks * 32 + quad * 8);

    f32x4 zz = {0.f, 0.f, 0.f, 0.f};
    f32x4 S[9];
#pragma unroll
    for (int jt = 0; jt < 9; jt++) S[jt] = zz;
    int kbase = qw0 - 128;

#pragma unroll
    for (int ks = 0; ks < 8; ks++) {
        bf16x8 kf[9];
#pragma unroll
        for (int jt = 0; jt < 9; jt++) {
            int krow = kbase + jt * 16 + lane16;
            krow = krow < 0 ? 0 : krow;
            kf[jt] = *(const bf16x8*)(kp + (size_t)krow * 256 + ks * 32 + quad * 8);
        }
#pragma unroll
        for (int jt = 0; jt < 9; jt++)
            S[jt] = __builtin_amdgcn_mfma_f32_16x16x32_bf16(qf[ks], kf[jt], S[jt], 0, 0, 0);
    }

    float m[4], l[4];
#pragma unroll
    for (int r = 0; r < 4; r++) m[r] = -1e30f;
#pragma unroll
    for (int jt = 0; jt < 9; jt++) {
        int kg = kbase + jt * 16 + lane16;
#pragma unroll
        for (int r = 0; r < 4; r++) {
            int qrow = qw0 + quad * 4 + r;
            bool ok = (kg >= 0) && (kg <= qrow) && (kg >= qrow - 128);
            float v = ok ? S[jt][r] * 0.0625f : -1e30f;
            S[jt][r] = v;
            m[r] = fmaxf(m[r], v);
        }
    }
#pragma unroll
    for (int d = 1; d < 16; d <<= 1)
#pragma unroll
        for (int r = 0; r < 4; r++)
            m[r] = fmaxf(m[r], __shfl_xor(m[r], d));
#pragma unroll
    for (int r = 0; r < 4; r++) l[r] = 0.f;
#pragma unroll
    for (int jt = 0; jt < 9; jt++)
#pragma unroll
        for (int r = 0; r < 4; r++) {
            float p = __expf(S[jt][r] - m[r]);
            S[jt][r] = p;
            l[r] += p;
        }
#pragma unroll
    for (int d = 1; d < 16; d <<= 1)
#pragma unroll
        for (int r = 0; r < 4; r++)
            l[r] += __shfl_xor(l[r], d);

#pragma unroll
    for (int jt = 0; jt < 9; jt++)
#pragma unroll
        for (int r = 0; r < 4; r++)
            Pw[(quad * 4 + r) * LDP + jt * 16 + lane16] = (bf16_t)S[jt][r];
    __syncthreads();

    f32x4 O[16];
#pragma unroll
    for (int nt = 0; nt < 16; nt++) O[nt] = zz;
#pragma unroll
    for (int ks = 0; ks < 5; ks++) {
        bf16x8 pf = *(const bf16x8*)&Pw[lane16 * LDP + ks * 32 + quad * 8];
        int kidx = kbase + ks * 32 + quad * 8;
        kidx = kidx < 0 ? 0 : kidx;
        kidx = kidx > (Tc - 8) ? (Tc - 8) : kidx;
#pragma unroll
        for (int nt = 0; nt < 16; nt++) {
            bf16x8 vf = *(const bf16x8*)(vp + (size_t)(nt * 16 + lane16) * Tc + kidx);
            O[nt] = __builtin_amdgcn_mfma_f32_16x16x32_bf16(pf, vf, O[nt], 0, 0, 0);
        }
    }

    float rl[4];
#pragma unroll
    for (int r = 0; r < 4; r++) rl[r] = 1.0f / l[r];
    int b = bh >> 2, h = bh & 3;
#pragma unroll
    for (int nt = 0; nt < 16; nt++)
#pragma unroll
        for (int r = 0; r < 4; r++) {
            int qrow = qw0 + quad * 4 + r;
            int dim = nt * 16 + lane16;
            ao[((size_t)(b * Tc + qrow)) * Dc + h * 256 + dim] = (bf16_t)(O[nt][r] * rl[r]);
        }
}

// ---------------------------------------------------------------------------
// Launch
// ---------------------------------------------------------------------------
extern "C" void kernel_launch(void* const* d_in, const int* in_sizes, int n_in,
                              void* d_out, int out_size, void* d_ws, size_t ws_size,
                              hipStream_t stream) {
    const float* x            = (const float*)d_in[0];
    const float* prev_eig     = (const float*)d_in[1];
    const float* norm1_g      = (const float*)d_in[2];
    const float* norm1_b      = (const float*)d_in[3];
    const float* in_proj_w    = (const float*)d_in[4];
    const float* memory_gate  = (const float*)d_in[5];
    const float* memory_proj_w= (const float*)d_in[6];
    const float* log_decay    = (const float*)d_in[7];
    const float* frequency    = (const float*)d_in[8];
    const float* coupling     = (const float*)d_in[9];
    const float* main_gate_w  = (const float*)d_in[10];
    const float* main_gate_b  = (const float*)d_in[11];
    const float* out_proj_w   = (const float*)d_in[12];
    const float* attn_norm_g  = (const float*)d_in[13];
    const float* attn_norm_b  = (const float*)d_in[14];
    const float* attn_in_w    = (const float*)d_in[15];
    const float* attn_in_b    = (const float*)d_in[16];
    const float* attn_out_w   = (const float*)d_in[17];
    const float* attn_out_b   = (const float*)d_in[18];
    const float* norm2_g      = (const float*)d_in[19];
    const float* norm2_b      = (const float*)d_in[20];
    const float* mlp_w1       = (const float*)d_in[21];
    const float* mlp_b1       = (const float*)d_in[22];
    const float* mlp_w2       = (const float*)d_in[23];
    const float* mlp_b2       = (const float*)d_in[24];

    char* ws = (char*)d_ws;
    bf16_t* ipw_b  = (bf16_t*)(ws + 0);
    bf16_t* mpw_b  = (bf16_t*)(ws + 262144);
    bf16_t* mgw_b  = (bf16_t*)(ws + 294912);
    bf16_t* opw_b  = (bf16_t*)(ws + 2392064);
    bf16_t* aiw_b  = (bf16_t*)(ws + 2654208);
    bf16_t* aow_b  = (bf16_t*)(ws + 8945664);
    bf16_t* w1_b   = (bf16_t*)(ws + 11042816);
    bf16_t* w2_b   = (bf16_t*)(ws + 19431424);
    bf16_t* prev_b = (bf16_t*)(ws + 27820032);
    const size_t OFF_ACTA = 29917184;
    const size_t OFF_BIG  = OFF_ACTA + 16777216;
    bf16_t* actA   = (bf16_t*)(ws + OFF_ACTA);
    float*  beta_c = (float*)(ws + OFF_BIG);
    float*  cbuf   = (float*)(ws + OFF_BIG + 4194304);
    bf16_t* eigb   = (bf16_t*)(ws + OFF_BIG + 8388608);
    bf16_t* qbuf   = (bf16_t*)(ws + OFF_BIG);
    bf16_t* kbuf   = (bf16_t*)(ws + OFF_BIG + 16777216);
    bf16_t* vtbuf  = (bf16_t*)(ws + OFF_BIG + 33554432);       // (b,h,d,t)
    bf16_t* mbuf   = (bf16_t*)(ws + OFF_BIG);

    float* out_x   = (float*)d_out;
    float* out_eig = out_x + (size_t)BTc * Dc;
    float* xres    = out_x;

    ConvArgs ca;
    ca.s[0] = ConvSeg{in_proj_w,     ipw_b,  131072};
    ca.s[1] = ConvSeg{memory_proj_w, mpw_b,  16384};
    ca.s[2] = ConvSeg{main_gate_w,   mgw_b,  1048576};
    ca.s[3] = ConvSeg{out_proj_w,    opw_b,  131072};
    ca.s[4] = ConvSeg{attn_in_w,     aiw_b,  3145728};
    ca.s[5] = ConvSeg{attn_out_w,    aow_b,  1048576};
    ca.s[6] = ConvSeg{mlp_w1,        w1_b,   4194304};
    ca.s[7] = ConvSeg{mlp_w2,        w2_b,   4194304};
    ca.s[8] = ConvSeg{prev_eig,      prev_b, 1048576};
    convert_kernel<<<dim3(4096, 9), 256, 0, stream>>>(ca);

    EpiParams ep{};

    ln_kernel<<<BTc, 256, 0, stream>>>(x, norm1_g, norm1_b, actA);
    gemm_beta<<<256, 256, 0, stream>>>(actA, ipw_b, prev_b, mpw_b, memory_gate, beta_c);
    scan_kernel<<<256, 64, 0, stream>>>(beta_c, log_decay, frequency, cbuf);
    coupling_kernel<<<4096, 256, 0, stream>>>(cbuf, coupling, out_eig, eigb);
    // x1 = x + sigmoid(xn@mgw^T + mgb) * (eig@opw^T)   [fused dual-K]
    ep = EpiParams{}; ep.bias = main_gate_b; ep.fin = x; ep.fout = xres;
    ep.a2 = eigb; ep.w2 = opw_b;
    gemm_tiled<6><<<(BTc/BM)*(Dc/BN), 256, 0, stream>>>(actA, mgw_b, BTc, Dc, Dc, ep);
    ln_kernel<<<BTc, 256, 0, stream>>>(xres, attn_norm_g, attn_norm_b, actA);
    // q,k (N=2048)
    ep = EpiParams{}; ep.bias = attn_in_b; ep.q = qbuf; ep.k = kbuf;
    gemm_tiled<3><<<(BTc/BM)*(2048/BN), 256, 0, stream>>>(actA, aiw_b, BTc, 2048, Dc, ep);
    // V^T (M=1024 dims, N=8192 tokens)
    ep = EpiParams{}; ep.bias = attn_in_b; ep.v = vtbuf;
    gemm_tiled<5><<<(Dc/BM)*(BTc/BN), 256, 0, stream>>>(aiw_b + (size_t)2048 * Dc, actA,
                                                        Dc, BTc, Dc, ep);
    // attention -> ao (reuses actA)
    attn_mfma<<<512, 256, 0, stream>>>(qbuf, kbuf, vtbuf, actA);
    // x2 = x1 + ao@aow^T + aob
    ep = EpiParams{}; ep.bias = attn_out_b; ep.fin = xres; ep.fout = xres;
    gemm_tiled<2><<<(BTc/BM)*(Dc/BN), 256, 0, stream>>>(actA, aow_b, BTc, Dc, Dc, ep);
    ln_kernel<<<BTc, 256, 0, stream>>>(xres, norm2_g, norm2_b, actA);
    // mlp1 (silu)
    ep = EpiParams{}; ep.bias = mlp_b1; ep.bout = mbuf;
    gemm_tiled<1><<<(BTc/BM)*(MLPc/BN), 256, 0, stream>>>(actA, w1_b, BTc, MLPc, Dc, ep);
    // mlp2 + residual
    ep = EpiParams{}; ep.bias = mlp_b2; ep.fin = xres; ep.fout = out_x;
    gemm_tiled<2><<<(BTc/BM)*(Dc/BN), 256, 0, stream>>>(mbuf, w2_b, BTc, Dc, MLPc, ep);

    (void)in_sizes; (void)n_in; (void)out_size; (void)ws_size;
}